// Round 3
// baseline (373.561 us; speedup 1.0000x reference)
//
#include <hip/hip_runtime.h>
#include <hip/hip_bf16.h>

#define NNODES 50000
#define NSAMP  25
#define FEAT   128

typedef __attribute__((ext_vector_type(4))) float  f32x4;
typedef __attribute__((ext_vector_type(8))) __bf16 bf16x8;

__device__ __forceinline__ bf16x8 cvt2(const f32x4 lo, const f32x4 hi) {
  bf16x8 r;
  r[0] = (__bf16)lo[0]; r[1] = (__bf16)lo[1];
  r[2] = (__bf16)lo[2]; r[3] = (__bf16)lo[3];
  r[4] = (__bf16)hi[0]; r[5] = (__bf16)hi[1];
  r[6] = (__bf16)hi[2]; r[7] = (__bf16)hi[3];
  return r;
}

// Wave-per-node mean-pool aggregator, B staged in LDS for occupancy:
//   out[n,f] = (1/25) * sum_s relu( sum_d e[nbr[n,s], d] * W[f,d] + b[f] )
// B (= W^T in MFMA fragment layout) lives in LDS as bf16: 32 KB, arranged
// [nt][kk][lane] x 16B so each (nt,kk) fragment is one stride-1 ds_read_b128.
// A rows gathered per node directly in fragment layout; pad rows (s>=25)
// predicated to zero (no wasted loads). 25->32 row padding, 2 M-tiles of 16.
// mfma_f32_16x16x32_bf16; C/D: col=lane&15, row=(lane>>4)*4+reg.
__global__ __launch_bounds__(256, 4)
void meanpool_mfma_kernel(const int* __restrict__ nbr,
                          const float* __restrict__ emb,
                          const float* __restrict__ W,
                          const float* __restrict__ b,
                          float* __restrict__ out)
{
  __shared__ bf16x8 Blds[8 * 4 * 64];   // 32 KB

  const int tid  = threadIdx.x;
  const int lane = tid & 63;
  const int wib  = tid >> 6;
  const int wid  = blockIdx.x * 4 + wib;
  const int nWaves = gridDim.x * 4;

  const int col  = lane & 15;   // f within f-tile (B/D col), s within M-tile (A row)
  const int quad = lane >> 4;   // 0..3: k-subblock for A/B, row-group for D
  const int coff = quad * 8;    // float offset within a K=32 chunk

  // ---- Fill B LDS: chunk c = nt*256 + kk*64 + l; holds
  //      W[nt*16 + (l&15)][kk*32 + (l>>4)*8 .. +7] as bf16x8
  for (int c = tid; c < 2048; c += 256) {
    const int nt = c >> 8;
    const int kk = (c >> 6) & 3;
    const int l  = c & 63;
    const int f  = nt * 16 + (l & 15);
    const int d0 = kk * 32 + (l >> 4) * 8;
    f32x4 lo = *(const f32x4*)(W + f * FEAT + d0);
    f32x4 hi = *(const f32x4*)(W + f * FEAT + d0 + 4);
    Blds[c] = cvt2(lo, hi);
  }

  // Bias per lane: bias[nt] = b[nt*16+col] (8 VGPRs; L1-cached loads)
  float bias[8];
  #pragma unroll
  for (int nt = 0; nt < 8; ++nt) bias[nt] = b[nt * 16 + col];

  __syncthreads();

  const float inv = 1.0f / (float)NSAMP;
  const bool  v1 = (16 + col) < NSAMP;   // M-tile 1 row validity (col < 9)
  const f32x4 zero4 = {0.f, 0.f, 0.f, 0.f};

  for (int n = wid; n < NNODES; n += nWaves) {
    const int* nb = nbr + n * NSAMP;
    const int i0 = nb[col];
    const int i1 = v1 ? nb[16 + col] : 0;
    const float* r0 = emb + (long long)i0 * FEAT;
    const float* r1 = emb + (long long)i1 * FEAT;

    // ---- Gather A fragments directly in MFMA layout (lane: 8 floats of its row)
    bf16x8 A0[4], A1[4];
    #pragma unroll
    for (int kk = 0; kk < 4; ++kk) {
      f32x4 lo0 = *(const f32x4*)(r0 + kk * 32 + coff);
      f32x4 hi0 = *(const f32x4*)(r0 + kk * 32 + coff + 4);
      A0[kk] = cvt2(lo0, hi0);
      f32x4 lo1 = zero4, hi1 = zero4;
      if (v1) {
        lo1 = *(const f32x4*)(r1 + kk * 32 + coff);
        hi1 = *(const f32x4*)(r1 + kk * 32 + coff + 4);
      }
      A1[kk] = cvt2(lo1, hi1);
    }

    float* orow = out + (long long)n * FEAT;

    #pragma unroll
    for (int nt = 0; nt < 8; ++nt) {
      f32x4 acc0 = {0.f, 0.f, 0.f, 0.f};
      f32x4 acc1 = {0.f, 0.f, 0.f, 0.f};
      #pragma unroll
      for (int kk = 0; kk < 4; ++kk) {
        const bf16x8 Bf = Blds[nt * 256 + kk * 64 + lane];
        acc0 = __builtin_amdgcn_mfma_f32_16x16x32_bf16(A0[kk], Bf, acc0, 0, 0, 0);
        acc1 = __builtin_amdgcn_mfma_f32_16x16x32_bf16(A1[kk], Bf, acc1, 0, 0, 0);
      }
      // Epilogue: bias + relu, mask pad rows (s >= 25), partial mean-pool
      float psum = 0.f;
      #pragma unroll
      for (int j = 0; j < 4; ++j) {
        psum += fmaxf(acc0[j] + bias[nt], 0.f);          // rows 0..15 all valid
        const int srow = 16 + quad * 4 + j;
        if (srow < NSAMP) psum += fmaxf(acc1[j] + bias[nt], 0.f);
      }
      // lanes l, l^16, l^32, l^48 share the same output column
      psum += __shfl_xor(psum, 16);
      psum += __shfl_xor(psum, 32);
      if (lane < 16) orow[nt * 16 + lane] = psum * inv;
    }
  }
}

extern "C" void kernel_launch(void* const* d_in, const int* in_sizes, int n_in,
                              void* d_out, int out_size, void* d_ws, size_t ws_size,
                              hipStream_t stream) {
  const int*   nbr = (const int*)d_in[0];
  const float* emb = (const float*)d_in[1];
  const float* W   = (const float*)d_in[2];
  const float* b   = (const float*)d_in[3];
  float* out = (float*)d_out;

  dim3 grid(2048), block(256);
  hipLaunchKernelGGL(meanpool_mfma_kernel, grid, block, 0, stream,
                     nbr, emb, W, b, out);
}

// Round 4
// 169.744 us; speedup vs baseline: 2.2007x; 2.2007x over previous
//
#include <hip/hip_runtime.h>
#include <hip/hip_bf16.h>

#define NNODES 50000
#define NSAMP  25
#define FEAT   128
#define TABROWS 100000

typedef __attribute__((ext_vector_type(4))) float  f32x4;
typedef __attribute__((ext_vector_type(2))) float  f32x2;
typedef __attribute__((ext_vector_type(8))) __bf16 bf16x8;

__device__ __forceinline__ bf16x8 cvt2(const f32x4 lo, const f32x4 hi) {
  bf16x8 r;
  r[0] = (__bf16)lo[0]; r[1] = (__bf16)lo[1];
  r[2] = (__bf16)lo[2]; r[3] = (__bf16)lo[3];
  r[4] = (__bf16)hi[0]; r[5] = (__bf16)hi[1];
  r[6] = (__bf16)hi[2]; r[7] = (__bf16)hi[3];
  return r;
}

// Pass 1: fp32 table -> bf16 table in workspace (halves gather traffic).
__global__ __launch_bounds__(256)
void cvt_table_kernel(const float* __restrict__ src, __bf16* __restrict__ dst, int n8)
{
  int i = blockIdx.x * blockDim.x + threadIdx.x;
  const int stride = gridDim.x * blockDim.x;
  for (; i < n8; i += stride) {
    f32x4 lo = ((const f32x4*)src)[2 * i];
    f32x4 hi = ((const f32x4*)src)[2 * i + 1];
    ((bf16x8*)dst)[i] = cvt2(lo, hi);
  }
}

// Pass 2: wave-per-node  out[n,f] = (1/25) * sum_s relu(e[nbr[n,s],:] @ W[f,:] + b[f])
// B (=W^T) in LDS in MFMA fragment layout (32 KB, one stride-1 ds_read_b128 per frag).
// A rows gathered straight from the bf16 table in fragment layout (one 16-B load
// per lane per K-step). Pad rows (s>=25) predicated off. Epilogue transposes the
// 8 f-tile psums through 2 KB wave-private LDS so each node is written with a
// single fully-coalesced 512-B store (fixes 8x write amplification seen in R3).
// mfma_f32_16x16x32_bf16; C/D: col=lane&15, row=(lane>>4)*4+reg.
template<int BF16TAB>
__global__ __launch_bounds__(256, 4)
void meanpool_mfma_kernel(const int* __restrict__ nbr,
                          const float* __restrict__ embf32,
                          const __bf16* __restrict__ embbf,
                          const float* __restrict__ W,
                          const float* __restrict__ b,
                          float* __restrict__ out)
{
  __shared__ bf16x8 Blds[8 * 4 * 64];   // 32 KB
  __shared__ float  Ot[4][128];         // 2 KB, per-wave transpose scratch

  const int tid  = threadIdx.x;
  const int lane = tid & 63;
  const int wib  = tid >> 6;
  const int wid  = blockIdx.x * 4 + wib;
  const int nWaves = gridDim.x * 4;

  const int col  = lane & 15;   // f within f-tile (B col), s within M-tile (A row)
  const int quad = lane >> 4;   // k-subblock for A/B, row-group for D
  const int coff = quad * 8;    // element offset within a K=32 chunk

  // ---- Fill B LDS: chunk c = nt*256 + kk*64 + l holds
  //      W[nt*16 + (l&15)][kk*32 + (l>>4)*8 .. +7] as bf16x8
  for (int c = tid; c < 2048; c += 256) {
    const int nt = c >> 8;
    const int kk = (c >> 6) & 3;
    const int l  = c & 63;
    const int f  = nt * 16 + (l & 15);
    const int d0 = kk * 32 + (l >> 4) * 8;
    f32x4 lo = *(const f32x4*)(W + f * FEAT + d0);
    f32x4 hi = *(const f32x4*)(W + f * FEAT + d0 + 4);
    Blds[c] = cvt2(lo, hi);
  }

  float bias[8];
  #pragma unroll
  for (int nt = 0; nt < 8; ++nt) bias[nt] = b[nt * 16 + col];

  __syncthreads();

  const float inv = 1.0f / (float)NSAMP;
  const bool  v1 = (16 + col) < NSAMP;   // M-tile-1 row validity (col < 9)
  const f32x4 zero4 = {0.f, 0.f, 0.f, 0.f};
  const bf16x8 zero8 = {};
  float* osc = &Ot[wib][0];

  for (int n = wid; n < NNODES; n += nWaves) {
    const int* nb = nbr + n * NSAMP;
    const int i0 = nb[col];
    const int i1 = v1 ? nb[16 + col] : 0;

    // ---- Gather A fragments directly in MFMA layout
    bf16x8 A0[4], A1[4];
    if (BF16TAB) {
      const __bf16* r0 = embbf + (long long)i0 * FEAT;
      const __bf16* r1 = embbf + (long long)i1 * FEAT;
      #pragma unroll
      for (int kk = 0; kk < 4; ++kk) {
        A0[kk] = *(const bf16x8*)(r0 + kk * 32 + coff);
        A1[kk] = v1 ? *(const bf16x8*)(r1 + kk * 32 + coff) : zero8;
      }
    } else {
      const float* r0 = embf32 + (long long)i0 * FEAT;
      const float* r1 = embf32 + (long long)i1 * FEAT;
      #pragma unroll
      for (int kk = 0; kk < 4; ++kk) {
        f32x4 lo0 = *(const f32x4*)(r0 + kk * 32 + coff);
        f32x4 hi0 = *(const f32x4*)(r0 + kk * 32 + coff + 4);
        A0[kk] = cvt2(lo0, hi0);
        f32x4 lo1 = zero4, hi1 = zero4;
        if (v1) {
          lo1 = *(const f32x4*)(r1 + kk * 32 + coff);
          hi1 = *(const f32x4*)(r1 + kk * 32 + coff + 4);
        }
        A1[kk] = cvt2(lo1, hi1);
      }
    }

    #pragma unroll
    for (int nt = 0; nt < 8; ++nt) {
      f32x4 acc0 = {0.f, 0.f, 0.f, 0.f};
      f32x4 acc1 = {0.f, 0.f, 0.f, 0.f};
      #pragma unroll
      for (int kk = 0; kk < 4; ++kk) {
        const bf16x8 Bf = Blds[nt * 256 + kk * 64 + lane];
        acc0 = __builtin_amdgcn_mfma_f32_16x16x32_bf16(A0[kk], Bf, acc0, 0, 0, 0);
        acc1 = __builtin_amdgcn_mfma_f32_16x16x32_bf16(A1[kk], Bf, acc1, 0, 0, 0);
      }
      // bias + relu, mask pad rows (s>=25), per-lane partial mean-pool
      float psum = 0.f;
      #pragma unroll
      for (int j = 0; j < 4; ++j) {
        psum += fmaxf(acc0[j] + bias[nt], 0.f);           // rows 0..15 all valid
        const int srow = 16 + quad * 4 + j;
        if (srow < NSAMP) psum += fmaxf(acc1[j] + bias[nt], 0.f);
      }
      psum += __shfl_xor(psum, 16);
      psum += __shfl_xor(psum, 32);
      if (lane < 16) osc[nt * 16 + lane] = psum * inv;    // wave-private LDS
    }
    // DS ops are in-order within a wave; wait for the writes' completion
    asm volatile("s_waitcnt lgkmcnt(0)" ::: "memory");
    const f32x2 o2 = *(const f32x2*)(osc + 2 * lane);
    *(f32x2*)(out + (long long)n * FEAT + 2 * lane) = o2;  // one 512-B store/node
  }
}

extern "C" void kernel_launch(void* const* d_in, const int* in_sizes, int n_in,
                              void* d_out, int out_size, void* d_ws, size_t ws_size,
                              hipStream_t stream) {
  const int*   nbr = (const int*)d_in[0];
  const float* emb = (const float*)d_in[1];
  const float* W   = (const float*)d_in[2];
  const float* b   = (const float*)d_in[3];
  float* out = (float*)d_out;

  const size_t tabBytes = (size_t)TABROWS * FEAT * sizeof(__bf16);
  const bool useBf16 = ws_size >= tabBytes;

  if (useBf16) {
    __bf16* tab = (__bf16*)d_ws;
    const int n8 = TABROWS * FEAT / 8;
    hipLaunchKernelGGL(cvt_table_kernel, dim3(2048), dim3(256), 0, stream,
                       emb, tab, n8);
    hipLaunchKernelGGL((meanpool_mfma_kernel<1>), dim3(2048), dim3(256), 0, stream,
                       nbr, emb, tab, W, b, out);
  } else {
    hipLaunchKernelGGL((meanpool_mfma_kernel<0>), dim3(2048), dim3(256), 0, stream,
                       nbr, emb, (const __bf16*)nullptr, W, b, out);
  }
}